// Round 1
// baseline (14116.902 us; speedup 1.0000x reference)
//
#include <hip/hip_runtime.h>

namespace {
constexpr int kN = 512;
constexpr int kB = 256;
constexpr int kPowerIters = 30;
constexpr int kFistaIters = 300;
}

// 256 MiB fallback in case d_ws is too small (BSS, zero file cost).
__device__ float g_Q_fallback[(size_t)kB * kN * kN];

// ---------------- block reductions (512 threads = 8 waves) ----------------

__device__ __forceinline__ float block_sum(float v, float* rs) {
#pragma unroll
  for (int off = 32; off > 0; off >>= 1) v += __shfl_down(v, off, 64);
  const int t = threadIdx.x;
  if ((t & 63) == 0) rs[t >> 6] = v;
  __syncthreads();
  if (t == 0) {
    float s = 0.f;
#pragma unroll
    for (int i = 0; i < 8; ++i) s += rs[i];
    rs[8] = s;
  }
  __syncthreads();
  const float r = rs[8];
  __syncthreads();  // protect rs for next call
  return r;
}

__device__ __forceinline__ float2 block_sum2(float a, float c, float2* rs2) {
#pragma unroll
  for (int off = 32; off > 0; off >>= 1) {
    a += __shfl_down(a, off, 64);
    c += __shfl_down(c, off, 64);
  }
  const int t = threadIdx.x;
  if ((t & 63) == 0) rs2[t >> 6] = make_float2(a, c);
  __syncthreads();
  if (t == 0) {
    float sa = 0.f, sc = 0.f;
#pragma unroll
    for (int i = 0; i < 8; ++i) { sa += rs2[i].x; sc += rs2[i].y; }
    rs2[8] = make_float2(sa, sc);
  }
  __syncthreads();
  const float2 r = rs2[8];
  __syncthreads();
  return r;
}

// u_i = sum_j Q[j][i] * y[j]  (Q bitwise-symmetric => u = Q y exactly).
// Thread t owns output i = t; j-space split 4 ways across thread quarters.
// Loads: lane-adjacent i -> fully coalesced float4 (1 KiB/wave/instr).
__device__ __forceinline__ float matvec512(const float4* __restrict__ Qv,
                                           const float* y_s, float* partial) {
  const int t = threadIdx.x;
  const int p = t & 127;       // float4 column index
  const int c = t >> 7;        // j-chunk 0..3
  const int jbeg = c << 7;
  const float4* q = Qv + (size_t)jbeg * 128 + p;
  float4 acc = make_float4(0.f, 0.f, 0.f, 0.f);
#pragma unroll 8
  for (int j = 0; j < 128; ++j) {
    const float yj = y_s[jbeg + j];   // wave-uniform -> LDS broadcast
    const float4 qq = q[j * 128];
    acc.x = fmaf(qq.x, yj, acc.x);
    acc.y = fmaf(qq.y, yj, acc.y);
    acc.z = fmaf(qq.z, yj, acc.z);
    acc.w = fmaf(qq.w, yj, acc.w);
  }
  *(float4*)(&partial[(c << 9) + (p << 2)]) = acc;
  __syncthreads();
  // conflict-free: consecutive t -> consecutive banks
  return partial[t] + partial[512 + t] + partial[1024 + t] + partial[1536 + t];
}

// Michelot's exact simplex-projection threshold (same theta as sort-based Duchi).
__device__ __forceinline__ float simplex_theta(float z, float2* rs2) {
  const float2 sc = block_sum2(z, 1.0f, rs2);
  float theta = (sc.x - 1.0f) * (1.0f / 512.0f);
  int prev = 512;
  for (int it = 0; it < 60; ++it) {
    const bool act = (z > theta);
    const float2 s = block_sum2(act ? z : 0.f, act ? 1.f : 0.f, rs2);
    const int cnt = (int)(s.y + 0.5f);
    if (cnt == prev) break;          // active set stable -> exact theta
    theta = (s.x - 1.0f) / (float)cnt;
    prev = cnt;
  }
  return theta;
}

// ---------------- fused per-batch solver: power iter + lambda + FISTA ----------------

__global__ __launch_bounds__(512) void solver_kernel(const float* __restrict__ Q,
                                                     const float* __restrict__ rets,
                                                     float* __restrict__ out) {
  __shared__ float y_s[kN];
  __shared__ float partial[4 * kN];
  __shared__ float rs[9];
  __shared__ float2 rs2[9];

  const int t = threadIdx.x;
  const int b = blockIdx.x;
  const float4* Qv = (const float4*)Q + (size_t)b * (kN * kN / 4);
  const float ret_t = rets[b * kN + t];

  // ---- power iteration: v <- normalize(Q v), 30 iters ----
  float v_t = 0.044194173824159216f;  // 1/sqrt(512)
  y_s[t] = v_t;
  __syncthreads();
  for (int it = 0; it < kPowerIters; ++it) {
    const float u = matvec512(Qv, y_s, partial);
    const float n2 = block_sum(u * u, rs);
    v_t = u / (sqrtf(n2) + 1e-12f);
    y_s[t] = v_t;
    __syncthreads();
  }
  // lam = v^T Q v ; eta = 1/(2 lam + 1e-8)
  const float u_l = matvec512(Qv, y_s, partial);
  const float lam = block_sum(v_t * u_l, rs);
  const float eta = 1.0f / (2.0f * lam + 1e-8f);

  // ---- FISTA ----
  float w_t = 1.0f / 512.0f;
  float y_t = w_t;
  float tf = 1.0f;
  y_s[t] = y_t;
  __syncthreads();
  for (int it = 0; it < kFistaIters; ++it) {
    const float u = matvec512(Qv, y_s, partial);   // Q y
    const float g = 2.0f * u - ret_t;
    const float z = y_t - eta * g;
    const float theta = simplex_theta(z, rs2);
    const float w_new = fmaxf(z - theta, 0.0f);
    const float t_new = 0.5f * (1.0f + sqrtf(1.0f + 4.0f * tf * tf));
    const float coef = (tf - 1.0f) / t_new;
    y_t = w_new + coef * (w_new - w_t);
    w_t = w_new;
    tf = t_new;
    y_s[t] = y_t;
    __syncthreads();
  }
  out[b * kN + t] = w_t;
}

// ---------------- Q = gamma^2 * C^T C, 128x128 tiles, fp32 ----------------
// grid: (16 tiles, 256 batches), block: 256 threads, 8x8 accumulators/thread.

__global__ __launch_bounds__(256) void build_q_kernel(const float* __restrict__ C,
                                                      const float* __restrict__ gamma,
                                                      float* __restrict__ Q) {
  __shared__ float As[8][128];
  __shared__ float Bs[8][128];
  const int b = blockIdx.y;
  const int ti = blockIdx.x >> 2;
  const int tj = blockIdx.x & 3;
  const int i0 = ti * 128, j0 = tj * 128;
  const float* Cb = C + (size_t)b * kN * kN;
  const float gg = gamma[b];
  const float g2 = gg * gg;
  const int tid = threadIdx.x;
  const int lr = tid >> 5;          // staging row 0..7
  const int lc = (tid & 31) << 2;   // staging col *4
  const int ty = tid >> 4;          // 0..15 -> i sub-tile
  const int tx = tid & 15;          // 0..15 -> j sub-tile

  float acc[8][8];
#pragma unroll
  for (int i = 0; i < 8; ++i)
#pragma unroll
    for (int j = 0; j < 8; ++j) acc[i][j] = 0.f;

  for (int k0 = 0; k0 < kN; k0 += 8) {
    const float4 av = *(const float4*)(Cb + (size_t)(k0 + lr) * kN + i0 + lc);
    const float4 bv = *(const float4*)(Cb + (size_t)(k0 + lr) * kN + j0 + lc);
    __syncthreads();
    *(float4*)(&As[lr][lc]) = av;
    *(float4*)(&Bs[lr][lc]) = bv;
    __syncthreads();
#pragma unroll
    for (int kk = 0; kk < 8; ++kk) {
      float a[8], bb[8];
      *(float4*)(&a[0]) = *(const float4*)(&As[kk][ty * 8]);
      *(float4*)(&a[4]) = *(const float4*)(&As[kk][ty * 8 + 4]);
      *(float4*)(&bb[0]) = *(const float4*)(&Bs[kk][tx * 8]);
      *(float4*)(&bb[4]) = *(const float4*)(&Bs[kk][tx * 8 + 4]);
#pragma unroll
      for (int ii = 0; ii < 8; ++ii)
#pragma unroll
        for (int jj = 0; jj < 8; ++jj)
          acc[ii][jj] = fmaf(a[ii], bb[jj], acc[ii][jj]);
    }
  }

  float* Qb = Q + (size_t)b * kN * kN;
#pragma unroll
  for (int ii = 0; ii < 8; ++ii) {
    const int i = i0 + ty * 8 + ii;
    float4 o0, o1;
    o0.x = acc[ii][0] * g2; o0.y = acc[ii][1] * g2;
    o0.z = acc[ii][2] * g2; o0.w = acc[ii][3] * g2;
    o1.x = acc[ii][4] * g2; o1.y = acc[ii][5] * g2;
    o1.z = acc[ii][6] * g2; o1.w = acc[ii][7] * g2;
    *(float4*)(Qb + (size_t)i * kN + j0 + tx * 8) = o0;
    *(float4*)(Qb + (size_t)i * kN + j0 + tx * 8 + 4) = o1;
  }
}

extern "C" void kernel_launch(void* const* d_in, const int* in_sizes, int n_in,
                              void* d_out, int out_size, void* d_ws, size_t ws_size,
                              hipStream_t stream) {
  (void)in_sizes; (void)n_in; (void)out_size;
  const float* rets  = (const float*)d_in[0];
  const float* cov   = (const float*)d_in[1];
  const float* gamma = (const float*)d_in[2];
  float* out = (float*)d_out;

  const size_t q_bytes = (size_t)kB * kN * kN * sizeof(float);  // 256 MiB
  float* Q = (float*)d_ws;
  if (ws_size < q_bytes) {
    void* sym = nullptr;
    hipGetSymbolAddress(&sym, HIP_SYMBOL(g_Q_fallback));  // host-side query, capture-safe
    Q = (float*)sym;
  }

  dim3 gb(16, kB, 1);
  build_q_kernel<<<gb, 256, 0, stream>>>(cov, gamma, Q);
  solver_kernel<<<kB, 512, 0, stream>>>(Q, rets, out);
}

// Round 2
// 7040.421 us; speedup vs baseline: 2.0051x; 2.0051x over previous
//
#include <hip/hip_runtime.h>
#include <hip/hip_fp16.h>

namespace {
constexpr int kN = 512;
constexpr int kB = 256;
constexpr int kPowerIters = 30;
constexpr int kFistaIters = 300;
}

// 128 MiB fallback in case d_ws is too small (BSS, zero file cost).
__device__ __half g_Q_fallback[(size_t)kB * kN * kN];

// ---------------- block reductions (512 threads = 8 waves) ----------------

__device__ __forceinline__ float block_sum(float v, float* rs) {
#pragma unroll
  for (int off = 32; off > 0; off >>= 1) v += __shfl_down(v, off, 64);
  const int t = threadIdx.x;
  if ((t & 63) == 0) rs[t >> 6] = v;
  __syncthreads();
  if (t == 0) {
    float s = 0.f;
#pragma unroll
    for (int i = 0; i < 8; ++i) s += rs[i];
    rs[8] = s;
  }
  __syncthreads();
  const float r = rs[8];
  __syncthreads();  // protect rs for next call
  return r;
}

__device__ __forceinline__ float2 block_sum2(float a, float c, float2* rs2) {
#pragma unroll
  for (int off = 32; off > 0; off >>= 1) {
    a += __shfl_down(a, off, 64);
    c += __shfl_down(c, off, 64);
  }
  const int t = threadIdx.x;
  if ((t & 63) == 0) rs2[t >> 6] = make_float2(a, c);
  __syncthreads();
  if (t == 0) {
    float sa = 0.f, sc = 0.f;
#pragma unroll
    for (int i = 0; i < 8; ++i) { sa += rs2[i].x; sc += rs2[i].y; }
    rs2[8] = make_float2(sa, sc);
  }
  __syncthreads();
  const float2 r = rs2[8];
  __syncthreads();
  return r;
}

// u_i = sum_j Q[j][i] * y[j], Q stored fp16 row-major (rows j, 512 halves = 1 KiB).
// Wave w owns j-chunk [64w, 64w+64); lane p loads 8 halves covering i in [8p, 8p+8).
// Each wave iteration reads one full 1 KiB row, perfectly coalesced (16 B/lane).
__device__ __forceinline__ float matvec512_h(const int4* __restrict__ Qv,
                                             const float* y_s, float* partial) {
  const int t = threadIdx.x;
  const int p = t & 63;        // int4 index within row: columns 8p..8p+7
  const int w = t >> 6;        // wave id = j-chunk
  const int jbeg = w << 6;
  const int4* q = Qv + (size_t)jbeg * 64 + p;  // row = 64 int4s
  float acc[8] = {0.f, 0.f, 0.f, 0.f, 0.f, 0.f, 0.f, 0.f};
#pragma unroll 4
  for (int j = 0; j < 64; ++j) {
    const float yj = y_s[jbeg + j];          // wave-uniform -> LDS broadcast
    const int4 raw = q[(size_t)j * 64];
    const __half2* h2 = reinterpret_cast<const __half2*>(&raw);
#pragma unroll
    for (int k = 0; k < 4; ++k) {
      const float2 f = __half22float2(h2[k]);
      acc[2 * k]     = fmaf(f.x, yj, acc[2 * k]);
      acc[2 * k + 1] = fmaf(f.y, yj, acc[2 * k + 1]);
    }
  }
  float4* pp = (float4*)&partial[(w << 9) + (p << 3)];
  pp[0] = make_float4(acc[0], acc[1], acc[2], acc[3]);
  pp[1] = make_float4(acc[4], acc[5], acc[6], acc[7]);
  __syncthreads();
  float u = 0.f;
#pragma unroll
  for (int w2 = 0; w2 < 8; ++w2) u += partial[(w2 << 9) + t];
  return u;
}

// Michelot's exact simplex-projection threshold (same theta as sort-based Duchi).
__device__ __forceinline__ float simplex_theta(float z, float2* rs2) {
  const float2 sc = block_sum2(z, 1.0f, rs2);
  float theta = (sc.x - 1.0f) * (1.0f / 512.0f);
  int prev = 512;
  for (int it = 0; it < 60; ++it) {
    const bool act = (z > theta);
    const float2 s = block_sum2(act ? z : 0.f, act ? 1.f : 0.f, rs2);
    const int cnt = (int)(s.y + 0.5f);
    if (cnt == prev) break;          // active set stable -> exact theta
    theta = (s.x - 1.0f) / (float)cnt;
    prev = cnt;
  }
  return theta;
}

// ---------------- fused per-batch solver: power iter + lambda + FISTA ----------------

__global__ __launch_bounds__(512) void solver_kernel(const __half* __restrict__ Q,
                                                     const float* __restrict__ rets,
                                                     float* __restrict__ out) {
  __shared__ float y_s[kN];
  __shared__ float partial[8 * kN];   // 16 KiB
  __shared__ float rs[9];
  __shared__ float2 rs2[9];

  const int t = threadIdx.x;
  const int b = blockIdx.x;
  const int4* Qv = (const int4*)(Q + (size_t)b * kN * kN);
  const float ret_t = rets[b * kN + t];

  // ---- power iteration: v <- normalize(Q v), 30 iters ----
  float v_t = 0.044194173824159216f;  // 1/sqrt(512)
  y_s[t] = v_t;
  __syncthreads();
  for (int it = 0; it < kPowerIters; ++it) {
    const float u = matvec512_h(Qv, y_s, partial);
    const float n2 = block_sum(u * u, rs);
    v_t = u / (sqrtf(n2) + 1e-12f);
    y_s[t] = v_t;
    __syncthreads();
  }
  // lam = v^T Q v ; eta = 1/(2 lam + 1e-8)
  const float u_l = matvec512_h(Qv, y_s, partial);
  const float lam = block_sum(v_t * u_l, rs);
  const float eta = 1.0f / (2.0f * lam + 1e-8f);

  // ---- FISTA ----
  float w_t = 1.0f / 512.0f;
  float y_t = w_t;
  float tf = 1.0f;
  y_s[t] = y_t;
  __syncthreads();
  for (int it = 0; it < kFistaIters; ++it) {
    const float u = matvec512_h(Qv, y_s, partial);   // Q y
    const float g = 2.0f * u - ret_t;
    const float z = y_t - eta * g;
    const float theta = simplex_theta(z, rs2);
    const float w_new = fmaxf(z - theta, 0.0f);
    const float t_new = 0.5f * (1.0f + sqrtf(1.0f + 4.0f * tf * tf));
    const float coef = (tf - 1.0f) / t_new;
    y_t = w_new + coef * (w_new - w_t);
    w_t = w_new;
    tf = t_new;
    y_s[t] = y_t;
    __syncthreads();
  }
  out[b * kN + t] = w_t;
}

// ---------------- Q = gamma^2 * C^T C, fp32 compute, fp16 store ----------------
// grid: (16 tiles, 256 batches), block: 256 threads, 8x8 accumulators/thread.

__global__ __launch_bounds__(256) void build_q_kernel(const float* __restrict__ C,
                                                      const float* __restrict__ gamma,
                                                      __half* __restrict__ Q) {
  __shared__ float As[8][128];
  __shared__ float Bs[8][128];
  const int b = blockIdx.y;
  const int ti = blockIdx.x >> 2;
  const int tj = blockIdx.x & 3;
  const int i0 = ti * 128, j0 = tj * 128;
  const float* Cb = C + (size_t)b * kN * kN;
  const float gg = gamma[b];
  const float g2 = gg * gg;
  const int tid = threadIdx.x;
  const int lr = tid >> 5;          // staging row 0..7
  const int lc = (tid & 31) << 2;   // staging col *4
  const int ty = tid >> 4;          // 0..15 -> i sub-tile
  const int tx = tid & 15;          // 0..15 -> j sub-tile

  float acc[8][8];
#pragma unroll
  for (int i = 0; i < 8; ++i)
#pragma unroll
    for (int j = 0; j < 8; ++j) acc[i][j] = 0.f;

  for (int k0 = 0; k0 < kN; k0 += 8) {
    const float4 av = *(const float4*)(Cb + (size_t)(k0 + lr) * kN + i0 + lc);
    const float4 bv = *(const float4*)(Cb + (size_t)(k0 + lr) * kN + j0 + lc);
    __syncthreads();
    *(float4*)(&As[lr][lc]) = av;
    *(float4*)(&Bs[lr][lc]) = bv;
    __syncthreads();
#pragma unroll
    for (int kk = 0; kk < 8; ++kk) {
      float a[8], bb[8];
      *(float4*)(&a[0]) = *(const float4*)(&As[kk][ty * 8]);
      *(float4*)(&a[4]) = *(const float4*)(&As[kk][ty * 8 + 4]);
      *(float4*)(&bb[0]) = *(const float4*)(&Bs[kk][tx * 8]);
      *(float4*)(&bb[4]) = *(const float4*)(&Bs[kk][tx * 8 + 4]);
#pragma unroll
      for (int ii = 0; ii < 8; ++ii)
#pragma unroll
        for (int jj = 0; jj < 8; ++jj)
          acc[ii][jj] = fmaf(a[ii], bb[jj], acc[ii][jj]);
    }
  }

  __half* Qb = Q + (size_t)b * kN * kN;
#pragma unroll
  for (int ii = 0; ii < 8; ++ii) {
    const int i = i0 + ty * 8 + ii;
    __half hv[8];
#pragma unroll
    for (int jj = 0; jj < 8; ++jj) hv[jj] = __float2half(acc[ii][jj] * g2);
    *(int4*)(Qb + (size_t)i * kN + j0 + tx * 8) = *(const int4*)hv;
  }
}

extern "C" void kernel_launch(void* const* d_in, const int* in_sizes, int n_in,
                              void* d_out, int out_size, void* d_ws, size_t ws_size,
                              hipStream_t stream) {
  (void)in_sizes; (void)n_in; (void)out_size;
  const float* rets  = (const float*)d_in[0];
  const float* cov   = (const float*)d_in[1];
  const float* gamma = (const float*)d_in[2];
  float* out = (float*)d_out;

  const size_t q_bytes = (size_t)kB * kN * kN * sizeof(__half);  // 128 MiB
  __half* Q = (__half*)d_ws;
  if (ws_size < q_bytes) {
    void* sym = nullptr;
    hipGetSymbolAddress(&sym, HIP_SYMBOL(g_Q_fallback));  // host-side query, capture-safe
    Q = (__half*)sym;
  }

  dim3 gb(16, kB, 1);
  build_q_kernel<<<gb, 256, 0, stream>>>(cov, gamma, Q);
  solver_kernel<<<kB, 512, 0, stream>>>(Q, rets, out);
}

// Round 3
// 2890.791 us; speedup vs baseline: 4.8834x; 2.4355x over previous
//
#include <hip/hip_runtime.h>
#include <hip/hip_fp16.h>

namespace {
constexpr int kN = 512;
constexpr int kB = 256;
constexpr int kPowerIters = 30;
constexpr int kFistaIters = 300;
}

// 128 MiB fallback in case d_ws is too small (BSS, zero file cost).
__device__ __half g_Q_fallback[(size_t)kB * kN * kN];

// ---- fma 8 fp16 elements (one int4) against wave-uniform scalar ----
__device__ __forceinline__ void fma8(const int4 raw, const float yj, float* acc) {
  const __half2* h2 = reinterpret_cast<const __half2*>(&raw);
#pragma unroll
  for (int k = 0; k < 4; ++k) {
    const float2 f = __half22float2(h2[k]);
    acc[2 * k]     = fmaf(f.x, yj, acc[2 * k]);
    acc[2 * k + 1] = fmaf(f.y, yj, acc[2 * k + 1]);
  }
}

// Shared tail: write per-wave partials, reduce 8 ways. One barrier.
__device__ __forceinline__ float matvec_tail(float* acc, float* partial) {
  const int t = threadIdx.x, lane = t & 63, w = t >> 6;
  float4* pp = (float4*)&partial[(w << 9) + (lane << 3)];
  pp[0] = make_float4(acc[0], acc[1], acc[2], acc[3]);
  pp[1] = make_float4(acc[4], acc[5], acc[6], acc[7]);
  __syncthreads();
  float u = 0.f;
#pragma unroll
  for (int w2 = 0; w2 < 8; ++w2) u += partial[(w2 << 9) + t];
  return u;
}

// Dense u = Q^T y (Q symmetric => = Q y). Wave w reads rows w, w+8, ...;
// lane l covers columns 8l..8l+7 (16 B/lane, each wave-load = one 1 KiB row).
__device__ __forceinline__ float matvec_dense(const int4* __restrict__ Qv,
                                              const float* yv, float* partial) {
  const int t = threadIdx.x, lane = t & 63, w = t >> 6;
  float acc[8] = {0.f, 0.f, 0.f, 0.f, 0.f, 0.f, 0.f, 0.f};
#pragma unroll 8
  for (int k = w; k < kN; k += 8) {
    const int4 raw = Qv[(size_t)k * 64 + lane];
    fma8(raw, yv[k], acc);
  }
  return matvec_tail(acc, partial);
}

// Sparse: only rows in the compacted (index,value) list. Exact vs dense.
__device__ __forceinline__ float matvec_sparse(const int4* __restrict__ Qv,
                                               const short* yi, const float* yv,
                                               const int nact, float* partial) {
  const int t = threadIdx.x, lane = t & 63, w = t >> 6;
  float acc[8] = {0.f, 0.f, 0.f, 0.f, 0.f, 0.f, 0.f, 0.f};
#pragma unroll 2
  for (int k = w; k < nact; k += 8) {
    const int row = yi[k];                      // wave-uniform -> LDS broadcast
    const int4 raw = Qv[(size_t)row * 64 + lane];
    fma8(raw, yv[k], acc);
  }
  return matvec_tail(acc, partial);
}

// ---------------- fused per-batch solver ----------------

__global__ __launch_bounds__(512) void solver_kernel(const __half* __restrict__ Q,
                                                     const float* __restrict__ rets,
                                                     float* __restrict__ out) {
  __shared__ float yv_s[kN];      // compacted y values (dense in power phase)
  __shared__ short yi_s[kN];      // compacted y indices
  __shared__ float z_s[kN];
  __shared__ float partial[8 * kN];   // 16 KiB
  __shared__ float red_s[8];
  __shared__ int cnt_s[8];
  __shared__ float theta_s;

  const int t = threadIdx.x;
  const int lane = t & 63;
  const int w = t >> 6;
  const int b = blockIdx.x;
  const int4* Qv = (const int4*)(Q + (size_t)b * kN * kN);
  const float ret_t = rets[b * kN + t];

  // ---- power iteration: v <- normalize(Q v), 30 iters (3 barriers/iter) ----
  float v_t = 0.044194173824159216f;  // 1/sqrt(512)
  yv_s[t] = v_t;
  __syncthreads();
  for (int it = 0; it < kPowerIters; ++it) {
    const float u = matvec_dense(Qv, yv_s, partial);   // 1 barrier inside
    float q = u * u;
#pragma unroll
    for (int m = 32; m > 0; m >>= 1) q += __shfl_xor(q, m, 64);
    if (lane == 0) red_s[w] = q;
    __syncthreads();
    float n2 = 0.f;
#pragma unroll
    for (int i = 0; i < 8; ++i) n2 += red_s[i];
    v_t = u / (sqrtf(n2) + 1e-12f);
    yv_s[t] = v_t;
    __syncthreads();
  }
  // lam = v^T Q v ; eta = 1/(2 lam + 1e-8)
  const float u_l = matvec_dense(Qv, yv_s, partial);
  float ql = v_t * u_l;
#pragma unroll
  for (int m = 32; m > 0; m >>= 1) ql += __shfl_xor(ql, m, 64);
  if (lane == 0) red_s[w] = ql;
  __syncthreads();
  float lam = 0.f;
#pragma unroll
  for (int i = 0; i < 8; ++i) lam += red_s[i];
  const float eta = 1.0f / (2.0f * lam + 1e-8f);

  // ---- FISTA (5 barriers/iter) ----
  float w_t = 1.0f / 512.0f;
  float y_t = w_t;
  float tf = 1.0f;
  int nact = kN;
  __syncthreads();              // red_s reads done before yv_s rewrite below
  yv_s[t] = y_t;
  yi_s[t] = (short)t;
  __syncthreads();
  for (int it = 0; it < kFistaIters; ++it) {
    const float u = (nact == kN) ? matvec_dense(Qv, yv_s, partial)
                                 : matvec_sparse(Qv, yi_s, yv_s, nact, partial);
    // note: dense path ignores yi ordering; valid only when list is identity —
    // which holds exactly when nact==512 straight after init; afterwards the
    // compacted list with nact==512 IS the identity (all 512 present, in order).
    const float z = y_t - eta * (2.0f * u - ret_t);
    z_s[t] = z;
    __syncthreads();            // bar B: z visible to wave 0

    if (w == 0) {
      // Michelot projection, wave-0 only, shuffle-butterfly reductions.
      float z8[8];
#pragma unroll
      for (int k = 0; k < 8; ++k) z8[k] = z_s[lane + (k << 6)];
      float s = 0.f;
#pragma unroll
      for (int k = 0; k < 8; ++k) s += z8[k];
#pragma unroll
      for (int m = 32; m > 0; m >>= 1) s += __shfl_xor(s, m, 64);
      float theta = (s - 1.0f) * (1.0f / 512.0f);
      int prev = 512;
      for (int r = 0; r < 60; ++r) {
        float ss = 0.f, cc = 0.f;
#pragma unroll
        for (int k = 0; k < 8; ++k) {
          if (z8[k] > theta) { ss += z8[k]; cc += 1.0f; }
        }
#pragma unroll
        for (int m = 32; m > 0; m >>= 1) {
          ss += __shfl_xor(ss, m, 64);
          cc += __shfl_xor(cc, m, 64);
        }
        const int cnt = (int)(cc + 0.5f);
        if (cnt == prev) break;     // active set stable -> exact theta
        theta = (ss - 1.0f) / cc;
        prev = cnt;
      }
      if (lane == 0) theta_s = theta;
    }
    __syncthreads();            // bar C: theta visible

    const float theta = theta_s;
    const float w_new = fmaxf(z - theta, 0.0f);
    const float t_new = 0.5f * (1.0f + sqrtf(1.0f + 4.0f * tf * tf));
    const float coef = (tf - 1.0f) / t_new;
    const float y_new = w_new + coef * (w_new - w_t);
    w_t = w_new;
    tf = t_new;
    y_t = y_new;

    // deterministic ballot compaction of supp(y_new)
    const bool nz = (y_new != 0.0f);
    const unsigned long long mask = __ballot(nz);
    const int pfx = __popcll(mask & ((1ull << lane) - 1ull));
    if (lane == 0) cnt_s[w] = __popcll(mask);
    __syncthreads();            // bar D: wave counts visible
    int off = 0, tot = 0;
#pragma unroll
    for (int i = 0; i < 8; ++i) {
      const int c = cnt_s[i];
      tot += c;
      if (i < w) off += c;
    }
    if (nz) {
      const int pos = off + pfx;
      yi_s[pos] = (short)t;
      yv_s[pos] = y_new;
    }
    nact = tot;
    __syncthreads();            // bar E: compact list visible for next matvec
  }
  out[b * kN + t] = w_t;
}

// ---------------- Q = gamma^2 * C^T C, fp32 compute, fp16 store ----------------
// grid: (16 tiles, 256 batches), block: 256 threads, 8x8 accumulators/thread.

__global__ __launch_bounds__(256) void build_q_kernel(const float* __restrict__ C,
                                                      const float* __restrict__ gamma,
                                                      __half* __restrict__ Q) {
  __shared__ float As[8][128];
  __shared__ float Bs[8][128];
  const int b = blockIdx.y;
  const int ti = blockIdx.x >> 2;
  const int tj = blockIdx.x & 3;
  const int i0 = ti * 128, j0 = tj * 128;
  const float* Cb = C + (size_t)b * kN * kN;
  const float gg = gamma[b];
  const float g2 = gg * gg;
  const int tid = threadIdx.x;
  const int lr = tid >> 5;          // staging row 0..7
  const int lc = (tid & 31) << 2;   // staging col *4
  const int ty = tid >> 4;          // 0..15 -> i sub-tile
  const int tx = tid & 15;          // 0..15 -> j sub-tile

  float acc[8][8];
#pragma unroll
  for (int i = 0; i < 8; ++i)
#pragma unroll
    for (int j = 0; j < 8; ++j) acc[i][j] = 0.f;

  for (int k0 = 0; k0 < kN; k0 += 8) {
    const float4 av = *(const float4*)(Cb + (size_t)(k0 + lr) * kN + i0 + lc);
    const float4 bv = *(const float4*)(Cb + (size_t)(k0 + lr) * kN + j0 + lc);
    __syncthreads();
    *(float4*)(&As[lr][lc]) = av;
    *(float4*)(&Bs[lr][lc]) = bv;
    __syncthreads();
#pragma unroll
    for (int kk = 0; kk < 8; ++kk) {
      float a[8], bb[8];
      *(float4*)(&a[0]) = *(const float4*)(&As[kk][ty * 8]);
      *(float4*)(&a[4]) = *(const float4*)(&As[kk][ty * 8 + 4]);
      *(float4*)(&bb[0]) = *(const float4*)(&Bs[kk][tx * 8]);
      *(float4*)(&bb[4]) = *(const float4*)(&Bs[kk][tx * 8 + 4]);
#pragma unroll
      for (int ii = 0; ii < 8; ++ii)
#pragma unroll
        for (int jj = 0; jj < 8; ++jj)
          acc[ii][jj] = fmaf(a[ii], bb[jj], acc[ii][jj]);
    }
  }

  __half* Qb = Q + (size_t)b * kN * kN;
#pragma unroll
  for (int ii = 0; ii < 8; ++ii) {
    const int i = i0 + ty * 8 + ii;
    __half hv[8];
#pragma unroll
    for (int jj = 0; jj < 8; ++jj) hv[jj] = __float2half(acc[ii][jj] * g2);
    *(int4*)(Qb + (size_t)i * kN + j0 + tx * 8) = *(const int4*)hv;
  }
}

extern "C" void kernel_launch(void* const* d_in, const int* in_sizes, int n_in,
                              void* d_out, int out_size, void* d_ws, size_t ws_size,
                              hipStream_t stream) {
  (void)in_sizes; (void)n_in; (void)out_size;
  const float* rets  = (const float*)d_in[0];
  const float* cov   = (const float*)d_in[1];
  const float* gamma = (const float*)d_in[2];
  float* out = (float*)d_out;

  const size_t q_bytes = (size_t)kB * kN * kN * sizeof(__half);  // 128 MiB
  __half* Q = (__half*)d_ws;
  if (ws_size < q_bytes) {
    void* sym = nullptr;
    hipGetSymbolAddress(&sym, HIP_SYMBOL(g_Q_fallback));  // host-side query, capture-safe
    Q = (__half*)sym;
  }

  dim3 gb(16, kB, 1);
  build_q_kernel<<<gb, 256, 0, stream>>>(cov, gamma, Q);
  solver_kernel<<<kB, 512, 0, stream>>>(Q, rets, out);
}

// Round 4
// 2180.616 us; speedup vs baseline: 6.4738x; 1.3257x over previous
//
#include <hip/hip_runtime.h>
#include <hip/hip_fp16.h>

namespace {
constexpr int kN = 512;
constexpr int kB = 256;
constexpr int kPowerIters = 30;
constexpr int kFistaIters = 300;
}

typedef __attribute__((ext_vector_type(8))) short bf16x8;
typedef __attribute__((ext_vector_type(4))) float f32x4;

// Device-global scratch (BSS): ignore d_ws entirely. All fully rewritten each call.
__device__ ushort g_Ct[(size_t)kB * kN * kN];          // bf16 C^T, 128 MiB
__device__ __half g_Q16[(size_t)kB * kN * kN];         // fp16 Q (gamma^2-scaled), 128 MiB
__device__ unsigned int g_Q8[(size_t)kB * kN * kN / 4];// fp8 e4m3 of Q/gamma^2, 64 MiB

// ---------------- transpose: C[b][k][i] fp32 -> Ct[b][i][k] bf16 ----------------

__device__ __forceinline__ ushort f32_to_bf16(float f) {
  unsigned int u = __float_as_uint(f);
  unsigned int r = u + 0x7FFFu + ((u >> 16) & 1u);   // RNE
  return (ushort)(r >> 16);
}

__global__ __launch_bounds__(256) void transpose_kernel(const float* __restrict__ C) {
  __shared__ ushort Ts[64][68];
  const int b = blockIdx.y;
  const int tk = blockIdx.x >> 3, ti = blockIdx.x & 7;
  const int k0 = tk * 64, i0 = ti * 64;
  const float* Cb = C + (size_t)b * kN * kN;
  ushort* Ct = g_Ct + (size_t)b * kN * kN;
  const int t = threadIdx.x;
  const int cq = t & 15;
  const int r0 = t >> 4;  // 0..15
#pragma unroll
  for (int p = 0; p < 4; ++p) {
    const int r = r0 + 16 * p;
    const float4 v = *(const float4*)(Cb + (size_t)(k0 + r) * kN + i0 + 4 * cq);
    ushort4 h;
    h.x = f32_to_bf16(v.x); h.y = f32_to_bf16(v.y);
    h.z = f32_to_bf16(v.z); h.w = f32_to_bf16(v.w);
    *(ushort4*)(&Ts[r][4 * cq]) = h;
  }
  __syncthreads();
#pragma unroll
  for (int p = 0; p < 4; ++p) {
    const int r = r0 + 16 * p;
    ushort4 h;
    h.x = Ts[4 * cq + 0][r];
    h.y = Ts[4 * cq + 1][r];
    h.z = Ts[4 * cq + 2][r];
    h.w = Ts[4 * cq + 3][r];
    *(ushort4*)(Ct + (size_t)(i0 + r) * kN + k0 + 4 * cq) = h;
  }
}

// ---------------- build: Q16 = gamma^2 * Ct * Ct^T via bf16 MFMA ----------------
// 128x128 tile/block, 4 waves in 2x2 quadrants, 4x4 16x16 MFMA tiles per wave.

__global__ __launch_bounds__(256) void build_q_kernel(const float* __restrict__ gamma) {
  __shared__ ushort As[128][40];   // [i_local][k_local], pitch 40 halves (16B-aligned rows)
  __shared__ ushort Bs[128][40];
  const int b = blockIdx.y;
  const int ti = blockIdx.x >> 2, tj = blockIdx.x & 3;
  const int i0 = ti * 128, j0 = tj * 128;
  const ushort* Ct = g_Ct + (size_t)b * kN * kN;
  const float gg = gamma[b];
  const float g2 = gg * gg;
  const int t = threadIdx.x;
  const int lane = t & 63, w = t >> 6;
  const int wr = w >> 1, wc = w & 1;
  const int m = lane & 15, q = lane >> 4;
  const int sr = t >> 2;   // 0..63 staging row
  const int ss = t & 3;    // 0..3 staging 8-half segment

  f32x4 acc[4][4];
#pragma unroll
  for (int g = 0; g < 4; ++g)
#pragma unroll
    for (int h = 0; h < 4; ++h) acc[g][h] = (f32x4){0.f, 0.f, 0.f, 0.f};

  for (int k0 = 0; k0 < kN; k0 += 32) {
    const int4 a0 = *(const int4*)(Ct + (size_t)(i0 + sr) * kN + k0 + 8 * ss);
    const int4 a1 = *(const int4*)(Ct + (size_t)(i0 + sr + 64) * kN + k0 + 8 * ss);
    const int4 b0 = *(const int4*)(Ct + (size_t)(j0 + sr) * kN + k0 + 8 * ss);
    const int4 b1 = *(const int4*)(Ct + (size_t)(j0 + sr + 64) * kN + k0 + 8 * ss);
    __syncthreads();
    *(int4*)(&As[sr][8 * ss]) = a0;
    *(int4*)(&As[sr + 64][8 * ss]) = a1;
    *(int4*)(&Bs[sr][8 * ss]) = b0;
    *(int4*)(&Bs[sr + 64][8 * ss]) = b1;
    __syncthreads();
    bf16x8 fa[4], fb[4];
#pragma unroll
    for (int g = 0; g < 4; ++g)
      fa[g] = *(const bf16x8*)(&As[64 * wr + 16 * g + m][8 * q]);
#pragma unroll
    for (int h = 0; h < 4; ++h)
      fb[h] = *(const bf16x8*)(&Bs[64 * wc + 16 * h + m][8 * q]);
#pragma unroll
    for (int g = 0; g < 4; ++g)
#pragma unroll
      for (int h = 0; h < 4; ++h)
        acc[g][h] = __builtin_amdgcn_mfma_f32_16x16x32_bf16(fa[g], fb[h], acc[g][h], 0, 0, 0);
  }

  __half* Qb = g_Q16 + (size_t)b * kN * kN;
#pragma unroll
  for (int g = 0; g < 4; ++g) {
#pragma unroll
    for (int h = 0; h < 4; ++h) {
      const int col = j0 + 64 * wc + 16 * h + m;
      const int rbase = i0 + 64 * wr + 16 * g + 4 * q;
#pragma unroll
      for (int r = 0; r < 4; ++r)
        Qb[(size_t)(rbase + r) * kN + col] = __float2half(acc[g][h][r] * g2);
    }
  }
}

// ---------------- q8: fp8 e4m3 copy of Q16 / gamma^2 (for power iteration) ------

__global__ __launch_bounds__(256) void q8_kernel(const float* __restrict__ gamma) {
  const int b = blockIdx.x;
  const float gg = gamma[b];
  const float inv = 1.0f / (gg * gg);
  const __half* Qb = g_Q16 + (size_t)b * kN * kN;
  unsigned int* q8 = g_Q8 + (size_t)b * kN * kN / 4;
  const int t = threadIdx.x;
  for (int idx = t; idx < kN * kN / 8; idx += 256) {
    const int4 raw = *(const int4*)(Qb + (size_t)idx * 8);
    const __half2* h2 = (const __half2*)&raw;
    float f[8];
#pragma unroll
    for (int k = 0; k < 4; ++k) {
      const float2 ff = __half22float2(h2[k]);
      f[2 * k] = ff.x * inv;
      f[2 * k + 1] = ff.y * inv;
    }
    unsigned int w0 = 0, w1 = 0;
    w0 = __builtin_amdgcn_cvt_pk_fp8_f32(f[0], f[1], w0, false);
    w0 = __builtin_amdgcn_cvt_pk_fp8_f32(f[2], f[3], w0, true);
    w1 = __builtin_amdgcn_cvt_pk_fp8_f32(f[4], f[5], w1, false);
    w1 = __builtin_amdgcn_cvt_pk_fp8_f32(f[6], f[7], w1, true);
    *(uint2*)(q8 + (size_t)idx * 2) = make_uint2(w0, w1);
  }
}

// ---------------- solver helpers ----------------

__device__ __forceinline__ void fma8(const int4 raw, const float yj, float* acc) {
  const __half2* h2 = reinterpret_cast<const __half2*>(&raw);
#pragma unroll
  for (int k = 0; k < 4; ++k) {
    const float2 f = __half22float2(h2[k]);
    acc[2 * k]     = fmaf(f.x, yj, acc[2 * k]);
    acc[2 * k + 1] = fmaf(f.y, yj, acc[2 * k + 1]);
  }
}

// Write per-wave partials + barrier. partial[w*512 + i] = wave w's share of output i.
__device__ __forceinline__ void partials_out(float* acc, float* partial) {
  const int t = threadIdx.x, lane = t & 63, w = t >> 6;
  float4* pp = (float4*)&partial[(w << 9) + (lane << 3)];
  pp[0] = make_float4(acc[0], acc[1], acc[2], acc[3]);
  pp[1] = make_float4(acc[4], acc[5], acc[6], acc[7]);
  __syncthreads();
}

__device__ __forceinline__ float tail_read(const float* partial) {
  const int t = threadIdx.x;
  float u = 0.f;
#pragma unroll
  for (int w2 = 0; w2 < 8; ++w2) u += partial[(w2 << 9) + t];
  return u;
}

// Dense fp8 matvec (power phase): row k = 512 B, lane covers cols 8*lane..8*lane+7.
__device__ __forceinline__ float matvec_dense8(const uint2* __restrict__ Q8,
                                               const float* yv, float* partial) {
  const int t = threadIdx.x, lane = t & 63, w = t >> 6;
  float acc[8] = {0.f, 0.f, 0.f, 0.f, 0.f, 0.f, 0.f, 0.f};
#pragma unroll 4
  for (int k = w; k < kN; k += 8) {
    const uint2 raw = Q8[(size_t)k * 64 + lane];
    const float yj = yv[k];
    acc[0] = fmaf(__builtin_amdgcn_cvt_f32_fp8(raw.x, 0), yj, acc[0]);
    acc[1] = fmaf(__builtin_amdgcn_cvt_f32_fp8(raw.x, 1), yj, acc[1]);
    acc[2] = fmaf(__builtin_amdgcn_cvt_f32_fp8(raw.x, 2), yj, acc[2]);
    acc[3] = fmaf(__builtin_amdgcn_cvt_f32_fp8(raw.x, 3), yj, acc[3]);
    acc[4] = fmaf(__builtin_amdgcn_cvt_f32_fp8(raw.y, 0), yj, acc[4]);
    acc[5] = fmaf(__builtin_amdgcn_cvt_f32_fp8(raw.y, 1), yj, acc[5]);
    acc[6] = fmaf(__builtin_amdgcn_cvt_f32_fp8(raw.y, 2), yj, acc[6]);
    acc[7] = fmaf(__builtin_amdgcn_cvt_f32_fp8(raw.y, 3), yj, acc[7]);
  }
  partials_out(acc, partial);
  return tail_read(partial);
}

// Dense fp16 matvec (Rayleigh pass).
__device__ __forceinline__ float matvec_dense16(const int4* __restrict__ Qv,
                                                const float* yv, float* partial) {
  const int t = threadIdx.x, lane = t & 63, w = t >> 6;
  float acc[8] = {0.f, 0.f, 0.f, 0.f, 0.f, 0.f, 0.f, 0.f};
#pragma unroll 8
  for (int k = w; k < kN; k += 8) {
    const int4 raw = Qv[(size_t)k * 64 + lane];
    fma8(raw, yv[k], acc);
  }
  partials_out(acc, partial);
  return tail_read(partial);
}

// Sparse fp16 matvec: partials only (wave 0 reduces).
__device__ __forceinline__ void matvec_sparse_partials(const int4* __restrict__ Qv,
                                                       const short* yi, const float* yv,
                                                       const int nact, float* partial) {
  const int t = threadIdx.x, lane = t & 63, w = t >> 6;
  float acc[8] = {0.f, 0.f, 0.f, 0.f, 0.f, 0.f, 0.f, 0.f};
#pragma unroll 2
  for (int k = w; k < nact; k += 8) {
    const int row = yi[k];
    const int4 raw = Qv[(size_t)row * 64 + lane];
    fma8(raw, yv[k], acc);
  }
  partials_out(acc, partial);
}

// ---------------- fused per-batch solver ----------------

__global__ __launch_bounds__(512) void solver_kernel(const float* __restrict__ rets,
                                                     float* __restrict__ out) {
  __shared__ float yv_s[kN];
  __shared__ short yi_s[kN];
  __shared__ float partial[8 * kN];  // 16 KiB
  __shared__ float red_s[8];
  __shared__ int nact_s;

  const int t = threadIdx.x;
  const int lane = t & 63;
  const int w = t >> 6;
  const int b = blockIdx.x;
  const int4* Q16v = (const int4*)(g_Q16 + (size_t)b * kN * kN);
  const uint2* Q8v = (const uint2*)g_Q8 + (size_t)b * (kN * kN / 8);

  // ---- power iteration on fp8 Q (30 iters) ----
  float v_t = 0.044194173824159216f;  // 1/sqrt(512)
  yv_s[t] = v_t;
  __syncthreads();
  for (int it = 0; it < kPowerIters; ++it) {
    const float u = matvec_dense8(Q8v, yv_s, partial);
    float qq = u * u;
#pragma unroll
    for (int m = 32; m > 0; m >>= 1) qq += __shfl_xor(qq, m, 64);
    if (lane == 0) red_s[w] = qq;
    __syncthreads();
    float n2 = 0.f;
#pragma unroll
    for (int i = 0; i < 8; ++i) n2 += red_s[i];
    v_t = u / (sqrtf(n2) + 1e-12f);
    yv_s[t] = v_t;
    __syncthreads();
  }
  // ---- Rayleigh on fp16 Q: lam = v^T Q v (2nd-order robust to v error) ----
  const float u_l = matvec_dense16(Q16v, yv_s, partial);
  float ql = v_t * u_l;
#pragma unroll
  for (int m = 32; m > 0; m >>= 1) ql += __shfl_xor(ql, m, 64);
  if (lane == 0) red_s[w] = ql;
  __syncthreads();
  float lam = 0.f;
#pragma unroll
  for (int i = 0; i < 8; ++i) lam += red_s[i];
  const float eta = 1.0f / (2.0f * 1.06f * lam + 1e-8f);  // 1.06 safety: fp8 direction noise

  // ---- FISTA: wave0 owns all scalar state; 2 barriers/iter ----
  float w8[8], y8[8], r8[8];
  float tf = 1.0f;
  __syncthreads();              // red_s reads done before shared rewrites
  yv_s[t] = 1.0f / 512.0f;
  yi_s[t] = (short)t;
  if (t == 0) nact_s = kN;
  if (w == 0) {
#pragma unroll
    for (int c = 0; c < 8; ++c) {
      w8[c] = 1.0f / 512.0f;
      y8[c] = 1.0f / 512.0f;
      r8[c] = rets[b * kN + 64 * c + lane];
    }
  }
  __syncthreads();

  for (int it = 0; it < kFistaIters; ++it) {
    const int na = nact_s;
    matvec_sparse_partials(Q16v, yi_s, yv_s, na, partial);  // barrier inside

    if (w == 0) {
      // reduce partials + gradient step (i = 64c + lane)
      float z8[8];
#pragma unroll
      for (int c = 0; c < 8; ++c) {
        float u = 0.f;
#pragma unroll
        for (int ww = 0; ww < 8; ++ww) u += partial[(ww << 9) + (c << 6) + lane];
        z8[c] = y8[c] - eta * (2.0f * u - r8[c]);
      }
      // Michelot projection threshold (shuffle-only)
      float s = 0.f;
#pragma unroll
      for (int c = 0; c < 8; ++c) s += z8[c];
#pragma unroll
      for (int m = 32; m > 0; m >>= 1) s += __shfl_xor(s, m, 64);
      float theta = (s - 1.0f) * (1.0f / 512.0f);
      int prev = kN;
      for (int r = 0; r < 60; ++r) {
        float ss = 0.f, cc = 0.f;
#pragma unroll
        for (int c = 0; c < 8; ++c)
          if (z8[c] > theta) { ss += z8[c]; cc += 1.0f; }
#pragma unroll
        for (int m = 32; m > 0; m >>= 1) {
          ss += __shfl_xor(ss, m, 64);
          cc += __shfl_xor(cc, m, 64);
        }
        const int cnt = (int)(cc + 0.5f);
        if (cnt == prev) break;
        theta = (ss - 1.0f) / cc;
        prev = cnt;
      }
      // update + deterministic compaction (i-ascending: c-major, lane-minor)
      const float t_new = 0.5f * (1.0f + sqrtf(1.0f + 4.0f * tf * tf));
      const float coef = (tf - 1.0f) / t_new;
      tf = t_new;
      int base = 0;
      const unsigned long long lt = (1ull << lane) - 1ull;
#pragma unroll
      for (int c = 0; c < 8; ++c) {
        const float wn = fmaxf(z8[c] - theta, 0.0f);
        const float yn = wn + coef * (wn - w8[c]);
        w8[c] = wn;
        y8[c] = yn;
        const bool nz = (yn != 0.0f);
        const unsigned long long mask = __ballot(nz);
        if (nz) {
          const int pos = base + __popcll(mask & lt);
          yi_s[pos] = (short)(64 * c + lane);
          yv_s[pos] = yn;
        }
        base += __popcll(mask);
      }
      if (lane == 0) nact_s = base;
    }
    __syncthreads();            // list + nact visible to all waves
  }

  if (w == 0) {
#pragma unroll
    for (int c = 0; c < 8; ++c) out[b * kN + 64 * c + lane] = w8[c];
  }
}

extern "C" void kernel_launch(void* const* d_in, const int* in_sizes, int n_in,
                              void* d_out, int out_size, void* d_ws, size_t ws_size,
                              hipStream_t stream) {
  (void)in_sizes; (void)n_in; (void)out_size; (void)d_ws; (void)ws_size;
  const float* rets  = (const float*)d_in[0];
  const float* cov   = (const float*)d_in[1];
  const float* gamma = (const float*)d_in[2];
  float* out = (float*)d_out;

  transpose_kernel<<<dim3(64, kB), 256, 0, stream>>>(cov);
  build_q_kernel<<<dim3(16, kB), 256, 0, stream>>>(gamma);
  q8_kernel<<<kB, 256, 0, stream>>>(gamma);
  solver_kernel<<<kB, 512, 0, stream>>>(rets, out);
}